// Round 5
// baseline (190.336 us; speedup 1.0000x reference)
//
#include <hip/hip_runtime.h>
#include <math.h>

// Sizes (fixed by the problem)
#define B_SZ 8
#define T_LEN 4096
#define D_IN 128
#define D_OUT 128
#define N_ST 256
#define BT (B_SZ * T_LEN)        // 32768
#define CHUNK 64                 // scan chunk length
#define NCHUNK (T_LEN / CHUNK)   // 64 chunks per sequence
#define NBLK (B_SZ * NCHUNK)     // 512 chunk-blocks == 2 blk/CU * 256 CU

typedef __attribute__((ext_vector_type(8))) short short8;
typedef __attribute__((ext_vector_type(4))) float f32x4;
typedef unsigned int uint;
typedef unsigned short ushort;

static __device__ __forceinline__ short f2bf(float f) {
  union { float f; uint u; } v; v.f = f;
  uint r = v.u + 0x7FFFu + ((v.u >> 16) & 1u);  // round-to-nearest-even
  return (short)(r >> 16);
}
static __device__ __forceinline__ float bf2f(uint h) {
  union { uint u; float f; } v; v.u = h << 16;
  return v.f;
}
static __device__ __forceinline__ uint pack2(float a, float b) {
  return (uint)(ushort)f2bf(a) | ((uint)(ushort)f2bf(b) << 16);
}
// 8 consecutive f32 -> short8 bf16; identical bits to the old k0 xbf pass
// (same pack2/f2bf rounding applied elementwise).
static __device__ __forceinline__ short8 cvt8(const float* __restrict__ p) {
  float4 a = *(const float4*)p;
  float4 b = *(const float4*)(p + 4);
  union { short8 s; uint4 u; } r;
  r.u.x = pack2(a.x, a.y); r.u.y = pack2(a.z, a.w);
  r.u.z = pack2(b.x, b.y); r.u.w = pack2(b.z, b.w);
  return r.s;
}

// ---------------------------------------------------------------------------
// k0w: weights + lampow only (R12 expressions VERBATIM) + barrier-counter
// zero (blk 384). Grid 385: blk<320 weight pack, [320,385) lampow rows.
// ---------------------------------------------------------------------------
__global__ __launch_bounds__(256) void k0w(
    const float* __restrict__ nu_log, const float* __restrict__ theta_log,
    const float* __restrict__ gamma_log,
    const float* __restrict__ B_re, const float* __restrict__ B_im,
    const float* __restrict__ C_re, const float* __restrict__ C_im,
    const float* __restrict__ Dm,
    short* __restrict__ Wf1, short* __restrict__ Wf2,
    float2* __restrict__ lampow2, uint* __restrict__ bar) {
  int blk = blockIdx.x;
  if (blk < 320) {
    int idx = blk * 256 + threadIdx.x;
    if (idx < 16 * 512 * 8) {
      int j = idx & 7, col = (idx >> 3) & 511, kg = idx >> 12;
      int k = kg * 8 + j;
      int n = col >> 1, ri = col & 1;
      float g = expf(gamma_log[n]);
      float v = g * (ri ? B_im[n * D_IN + k] : B_re[n * D_IN + k]);
      Wf1[idx] = f2bf(v);
    }
    if (idx < 80 * 128 * 8) {
      int j = idx & 7, d = (idx >> 3) & 127, kg = idx >> 10;
      int k = kg * 8 + j;
      float v;
      if (k < 512) {
        int n = k >> 1;
        v = (k & 1) ? -C_im[d * N_ST + n] : C_re[d * N_ST + n];
      } else {
        v = Dm[d * D_IN + (k - 512)];
      }
      Wf2[idx] = f2bf(v);
    }
  } else {
    int j = blk - 320;  // 0..64
    if (j == 64 && threadIdx.x == 0) *bar = 0;  // reset grid-barrier counter
    int n = threadIdx.x;
    float e_nu = expf(nu_log[n]);
    float phase = expf(theta_log[n]);
    float r = expf(-(float)j * e_nu);
    float a = (float)j * phase;
    float2 v; v.x = r * cosf(a); v.y = r * sinf(a);
    lampow2[j * N_ST + n] = v;
  }
}

// Software grid barrier (what grid.sync() is, minus the cooperative-launch
// dependency that graph capture broke in R19). Monotonic counter; target
// grows by NBLK per barrier. atomicAdd(bar,0) reads at the coherence point
// (a volatile load could spin on a stale XCD-local L2 line forever);
// __threadfence() emits the L2 writeback/invalidate for cross-XCD visibility.
static __device__ __forceinline__ void gridbar(uint* bar, uint target) {
  __syncthreads();
  if (threadIdx.x == 0) {
    __threadfence();                 // release: flush my E/P writes
    atomicAdd(bar, 1u);
    while (atomicAdd(bar, 0u) < target) __builtin_amdgcn_s_sleep(2);
    __threadfence();                 // acquire: invalidate stale L1/L2
  }
  __syncthreads();
}

// ---------------------------------------------------------------------------
// kF R20: R19 kF VERBATIM except grid.sync() -> gridbar() and normal launch.
// Grid 512 = exactly 2 blk/CU x 256 CU; LDS 65KB*2=130KB<=160KB and
// __launch_bounds__(256,2) guarantee full co-residency -> spin cannot starve.
//  phase 0: GEMM1 (kA-verbatim; A-frags cvt8 from x f32) -> bu
//  phase 1: in-place scan (R18-verbatim) + E store
//  --- gridbar(NBLK) ---
//  phase 2: blocks 0..7: carry scan across chunks (R16 kB FMA order) -> P
//  --- gridbar(2*NBLK) ---
//  phase 3: in-place carry fix-up (R18 phase-2 verbatim)
//  phase 4: GEMM2 (R18 phase-3 verbatim) -> y
// All producing expressions verbatim from passed rounds -> y bit-identical.
// ---------------------------------------------------------------------------
__global__ __launch_bounds__(256, 2) void kF(
    const float* __restrict__ x, const short* __restrict__ Wf1,
    const float2* __restrict__ lampow2, const short* __restrict__ Wf2,
    float2* __restrict__ E, float2* __restrict__ P, float* __restrict__ y,
    uint* __restrict__ bar) {
  __shared__ short bu[64 * 520];   // 65 KB -> 2 blk/CU

  int bc = blockIdx.x;             // chunk id 0..511
  size_t row0 = (size_t)bc * CHUNK;
  int tid = threadIdx.x;
  int lane = tid & 63, w = tid >> 6;
  int m = lane & 15, q = lane >> 4;

  // ---- phase 0: GEMM1 (kA-verbatim structure) ----
  f32x4 acc[32];
#pragma unroll
  for (int ct = 0; ct < 32; ++ct) acc[ct] = (f32x4){0.f, 0.f, 0.f, 0.f};

  const float* xrowf = x + (row0 + 16 * w + m) * D_IN;

  for (int ks = 0; ks < 4; ++ks) {
    short8 af = cvt8(xrowf + 32 * ks + 8 * q);
    const short* wbase = Wf1 + ((size_t)(4 * ks + q) * 512 + m) * 8;
#pragma unroll
    for (int ct = 0; ct < 32; ++ct) {
      short8 bf = *(const short8*)(wbase + 16 * ct * 8);
      acc[ct] = __builtin_amdgcn_mfma_f32_16x16x32_bf16(af, bf, acc[ct], 0, 0, 0);
    }
  }

#pragma unroll
  for (int ct = 0; ct < 32; ++ct) {
#pragma unroll
    for (int r = 0; r < 4; ++r) {
      bu[(16 * w + 4 * q + r) * 520 + 16 * ct + m] = f2bf(acc[ct][r]);
    }
  }
  __syncthreads();

  // ---- phase 1: local scan in place (R18-verbatim) + E (kA-verbatim) ----
  {
    int n = tid;
    float2 lam = lampow2[N_ST + n];  // lam^1
    float sre = 0.f, sim = 0.f;
    for (int j = 0; j < CHUNK; ++j) {
      uint p = ((const uint*)(bu + j * 520))[n];
      float br = bf2f(p & 0xffffu), bi = bf2f(p >> 16);
      float nr = fmaf(lam.x, sre, fmaf(-lam.y, sim, br));
      float ni = fmaf(lam.x, sim, fmaf(lam.y, sre, bi));
      sre = nr; sim = ni;
      ((uint*)(bu + j * 520))[n] = pack2(sre, sim);  // == old stored states bits
    }
    float2 e; e.x = sre; e.y = sim;
    E[bc * N_ST + n] = e;
  }
  gridbar(bar, NBLK);

  // ---- phase 2: carry scan across chunks (blocks 0..7; R16 kB order) ----
  if (bc < B_SZ) {
    int b = bc, n = tid;
    float2 lamL = lampow2[CHUNK * N_ST + n];
    float2 eb0, eb1, eb2, eb3, eb4, eb5, eb6, eb7;
    const float2* Eb = E + (size_t)b * NCHUNK * N_ST;
    eb0 = Eb[0 * N_ST + n]; eb1 = Eb[1 * N_ST + n];
    eb2 = Eb[2 * N_ST + n]; eb3 = Eb[3 * N_ST + n];
    eb4 = Eb[4 * N_ST + n]; eb5 = Eb[5 * N_ST + n];
    eb6 = Eb[6 * N_ST + n]; eb7 = Eb[7 * N_ST + n];
    float cre = 0.f, cim = 0.f;
#pragma unroll
    for (int c = 0; c < NCHUNK; ++c) {
      float2 pv; pv.x = cre; pv.y = cim;
      P[((size_t)b * NCHUNK + c) * N_ST + n] = pv;
      float2 e;
      switch (c & 7) {             // static after full unroll
        case 0: e = eb0; if (c + 8 < NCHUNK) eb0 = Eb[(c + 8) * N_ST + n]; break;
        case 1: e = eb1; if (c + 8 < NCHUNK) eb1 = Eb[(c + 8) * N_ST + n]; break;
        case 2: e = eb2; if (c + 8 < NCHUNK) eb2 = Eb[(c + 8) * N_ST + n]; break;
        case 3: e = eb3; if (c + 8 < NCHUNK) eb3 = Eb[(c + 8) * N_ST + n]; break;
        case 4: e = eb4; if (c + 8 < NCHUNK) eb4 = Eb[(c + 8) * N_ST + n]; break;
        case 5: e = eb5; if (c + 8 < NCHUNK) eb5 = Eb[(c + 8) * N_ST + n]; break;
        case 6: e = eb6; if (c + 8 < NCHUNK) eb6 = Eb[(c + 8) * N_ST + n]; break;
        default: e = eb7; if (c + 8 < NCHUNK) eb7 = Eb[(c + 8) * N_ST + n]; break;
      }
      float nre = fmaf(lamL.x, cre, fmaf(-lamL.y, cim, e.x));
      float nim = fmaf(lamL.x, cim, fmaf(lamL.y, cre, e.y));
      cre = nre; cim = nim;
    }
  }
  gridbar(bar, 2 * NBLK);

  // ---- phase 3: carry fix-up in place (R18 phase-2 verbatim) ----
  {
    int n4 = tid & 63, rblk = tid >> 6;
    float4 pA = *(const float4*)(P + (size_t)bc * N_ST + 4 * n4);      // p0,p1
    float4 pB = *(const float4*)(P + (size_t)bc * N_ST + 4 * n4 + 2);  // p2,p3
#pragma unroll
    for (int rr = 0; rr < 16; ++rr) {
      int row = rblk * 16 + rr;    // local row 0..63
      uint4 sp = *(const uint4*)(bu + row * 520 + 8 * n4);
      float4 lpa = *(const float4*)(lampow2 + ((size_t)(row + 1) * N_ST + 4 * n4));
      float4 lpb = *(const float4*)(lampow2 + ((size_t)(row + 1) * N_ST + 4 * n4 + 2));
      uint4 outv;
      {
        float sr = bf2f(sp.x & 0xffffu) + lpa.x * pA.x - lpa.y * pA.y;
        float si = bf2f(sp.x >> 16)     + lpa.x * pA.y + lpa.y * pA.x;
        outv.x = pack2(sr, si);
      }
      {
        float sr = bf2f(sp.y & 0xffffu) + lpa.z * pA.z - lpa.w * pA.w;
        float si = bf2f(sp.y >> 16)     + lpa.z * pA.w + lpa.w * pA.z;
        outv.y = pack2(sr, si);
      }
      {
        float sr = bf2f(sp.z & 0xffffu) + lpb.x * pB.x - lpb.y * pB.y;
        float si = bf2f(sp.z >> 16)     + lpb.x * pB.y + lpb.y * pB.x;
        outv.z = pack2(sr, si);
      }
      {
        float sr = bf2f(sp.w & 0xffffu) + lpb.z * pB.z - lpb.w * pB.w;
        float si = bf2f(sp.w >> 16)     + lpb.z * pB.w + lpb.w * pB.z;
        outv.w = pack2(sr, si);
      }
      *(uint4*)(bu + row * 520 + 8 * n4) = outv;
    }
  }
  __syncthreads();

  // ---- phase 4: GEMM2 (R18 phase-3 verbatim; xa via cvt8 from x) ----
  int rw = w & 1, ch = w >> 1;
  int arow0 = 32 * rw + m;

  short8 xa0[4], xa1[4];
#pragma unroll
  for (int t = 0; t < 4; ++t) {
    xa0[t] = cvt8(x + (row0 + arow0) * D_IN + 32 * t + 8 * q);
    xa1[t] = cvt8(x + (row0 + arow0 + 16) * D_IN + 32 * t + 8 * q);
  }

  f32x4 acc2[2][4];                // [row-tile][col-tile]
#pragma unroll
  for (int rt = 0; rt < 2; ++rt)
#pragma unroll
    for (int ci = 0; ci < 4; ++ci) acc2[rt][ci] = (f32x4){0.f, 0.f, 0.f, 0.f};

  for (int ks = 0; ks < 16; ++ks) {
    int g = 4 * ks + q;
    short8 af0 = *(const short8*)(bu + arow0 * 520 + 8 * g);
    short8 af1 = *(const short8*)(bu + (arow0 + 16) * 520 + 8 * g);
    const short* wbase = Wf2 + ((size_t)g * 128 + m) * 8;
#pragma unroll
    for (int ci = 0; ci < 4; ++ci) {
      int ctg = 4 * ch + ci;
      short8 bf = *(const short8*)(wbase + 16 * ctg * 8);
      acc2[0][ci] = __builtin_amdgcn_mfma_f32_16x16x32_bf16(af0, bf, acc2[0][ci], 0, 0, 0);
      acc2[1][ci] = __builtin_amdgcn_mfma_f32_16x16x32_bf16(af1, bf, acc2[1][ci], 0, 0, 0);
    }
  }
#pragma unroll
  for (int t = 0; t < 4; ++t) {
    int g = 64 + 4 * t + q;
    const short* wbase = Wf2 + ((size_t)g * 128 + m) * 8;
#pragma unroll
    for (int ci = 0; ci < 4; ++ci) {
      int ctg = 4 * ch + ci;
      short8 bf = *(const short8*)(wbase + 16 * ctg * 8);
      acc2[0][ci] = __builtin_amdgcn_mfma_f32_16x16x32_bf16(xa0[t], bf, acc2[0][ci], 0, 0, 0);
      acc2[1][ci] = __builtin_amdgcn_mfma_f32_16x16x32_bf16(xa1[t], bf, acc2[1][ci], 0, 0, 0);
    }
  }

#pragma unroll
  for (int ci = 0; ci < 4; ++ci) {
    int ctg = 4 * ch + ci;
#pragma unroll
    for (int rt = 0; rt < 2; ++rt) {
#pragma unroll
      for (int r = 0; r < 4; ++r) {
        y[(row0 + 32 * rw + 16 * rt + 4 * q + r) * D_OUT + 16 * ctg + m] = acc2[rt][ci][r];
      }
    }
  }
}

// ---------------------------------------------------------------------------
extern "C" void kernel_launch(void* const* d_in, const int* in_sizes, int n_in,
                              void* d_out, int out_size, void* d_ws, size_t ws_size,
                              hipStream_t stream) {
  const float* x         = (const float*)d_in[0];
  const float* nu_log    = (const float*)d_in[1];
  const float* theta_log = (const float*)d_in[2];
  const float* gamma_log = (const float*)d_in[3];
  const float* B_re      = (const float*)d_in[4];
  const float* B_im      = (const float*)d_in[5];
  const float* C_re      = (const float*)d_in[6];
  const float* C_im      = (const float*)d_in[7];
  const float* Dm        = (const float*)d_in[8];
  float* y = (float*)d_out;

  char* wp = (char*)d_ws;
  float2* lampow2 = (float2*)wp; wp += (size_t)(CHUNK + 1) * N_ST * sizeof(float2);
  short*  Wf1     = (short*)wp;  wp += (size_t)16 * 512 * 8 * sizeof(short);
  short*  Wf2     = (short*)wp;  wp += (size_t)80 * 128 * 8 * sizeof(short);
  float2* E       = (float2*)wp; wp += (size_t)NBLK * N_ST * sizeof(float2);
  float2* P       = (float2*)wp; wp += (size_t)NBLK * N_ST * sizeof(float2);
  uint*   bar     = (uint*)wp;   wp += 256;

  hipLaunchKernelGGL(k0w, dim3(385), dim3(256), 0, stream,
                     nu_log, theta_log, gamma_log, B_re, B_im, C_re, C_im,
                     Dm, Wf1, Wf2, lampow2, bar);
  hipLaunchKernelGGL(kF, dim3(NBLK), dim3(256), 0, stream,
                     x, Wf1, lampow2, Wf2, E, P, y, bar);
}

// Round 6
// 172.647 us; speedup vs baseline: 1.1025x; 1.1025x over previous
//
#include <hip/hip_runtime.h>
#include <math.h>

// Sizes (fixed by the problem)
#define B_SZ 8
#define T_LEN 4096
#define D_IN 128
#define D_OUT 128
#define N_ST 256
#define BT (B_SZ * T_LEN)        // 32768
#define CHUNK 64                 // scan chunk length
#define NCHUNK (T_LEN / CHUNK)   // 64 chunks per sequence
#define NBLK (B_SZ * NCHUNK)     // 512 chunk-blocks == 2 blk/CU * 256 CU

typedef __attribute__((ext_vector_type(8))) short short8;
typedef __attribute__((ext_vector_type(4))) float f32x4;
typedef unsigned int uint;
typedef unsigned short ushort;

static __device__ __forceinline__ short f2bf(float f) {
  union { float f; uint u; } v; v.f = f;
  uint r = v.u + 0x7FFFu + ((v.u >> 16) & 1u);  // round-to-nearest-even
  return (short)(r >> 16);
}
static __device__ __forceinline__ float bf2f(uint h) {
  union { uint u; float f; } v; v.u = h << 16;
  return v.f;
}
static __device__ __forceinline__ uint pack2(float a, float b) {
  return (uint)(ushort)f2bf(a) | ((uint)(ushort)f2bf(b) << 16);
}
// 8 consecutive f32 -> short8 bf16; identical bits to the old k0 xbf pass
// (same pack2/f2bf rounding applied elementwise).
static __device__ __forceinline__ short8 cvt8(const float* __restrict__ p) {
  float4 a = *(const float4*)p;
  float4 b = *(const float4*)(p + 4);
  union { short8 s; uint4 u; } r;
  r.u.x = pack2(a.x, a.y); r.u.y = pack2(a.z, a.w);
  r.u.z = pack2(b.x, b.y); r.u.w = pack2(b.z, b.w);
  return r.s;
}

// ---------------------------------------------------------------------------
// k0w: weights + lampow (R12 expressions VERBATIM) + per-chunk flag zeroing.
// Grid 385: blk<320 weight pack, [320,385) lampow rows. All blocks help zero
// the 64 KB flag region (visible to kF via kernel-boundary release).
// ---------------------------------------------------------------------------
__global__ __launch_bounds__(256) void k0w(
    const float* __restrict__ nu_log, const float* __restrict__ theta_log,
    const float* __restrict__ gamma_log,
    const float* __restrict__ B_re, const float* __restrict__ B_im,
    const float* __restrict__ C_re, const float* __restrict__ C_im,
    const float* __restrict__ Dm,
    short* __restrict__ Wf1, short* __restrict__ Wf2,
    float2* __restrict__ lampow2, uint* __restrict__ flags) {
  int blk = blockIdx.x;
  {
    int fi = blk * 256 + threadIdx.x;
    if (fi < NBLK * 32) flags[fi] = 0;   // 16384 uints = 64 KB
  }
  if (blk < 320) {
    int idx = blk * 256 + threadIdx.x;
    if (idx < 16 * 512 * 8) {
      int j = idx & 7, col = (idx >> 3) & 511, kg = idx >> 12;
      int k = kg * 8 + j;
      int n = col >> 1, ri = col & 1;
      float g = expf(gamma_log[n]);
      float v = g * (ri ? B_im[n * D_IN + k] : B_re[n * D_IN + k]);
      Wf1[idx] = f2bf(v);
    }
    if (idx < 80 * 128 * 8) {
      int j = idx & 7, d = (idx >> 3) & 127, kg = idx >> 10;
      int k = kg * 8 + j;
      float v;
      if (k < 512) {
        int n = k >> 1;
        v = (k & 1) ? -C_im[d * N_ST + n] : C_re[d * N_ST + n];
      } else {
        v = Dm[d * D_IN + (k - 512)];
      }
      Wf2[idx] = f2bf(v);
    }
  } else {
    int j = blk - 320;  // 0..64
    int n = threadIdx.x;
    float e_nu = expf(nu_log[n]);
    float phase = expf(theta_log[n]);
    float r = expf(-(float)j * e_nu);
    float a = (float)j * phase;
    float2 v; v.x = r * cosf(a); v.y = r * sinf(a);
    lampow2[j * N_ST + n] = v;
  }
}

// ---------------------------------------------------------------------------
// kF R21: no grid barriers. Decoupled per-chunk publication + forward-order
// lookback (kB-verbatim FMA order -> carry P bit-identical, kept in LDS).
//  phase 0: GEMM1 (kA-verbatim; A-frags cvt8 from x f32) -> bu
//  phase 1: in-place scan (R18-verbatim) + E store; publish flag[bc]
//           (R20-proven handshake: syncthreads -> threadfence -> atomicExch)
//  phase 2: wait for flags of own-batch chunks 0..c-1 (threads poll distinct
//           padded flag lines in parallel), threadfence, then kB-verbatim
//           forward recurrence over E[b,0..c-1] -> (cre,cim) -> Pl[n] in LDS
//  phase 3: in-place carry fix-up (R18 phase-2 verbatim; pA/pB from Pl)
//  phase 4: GEMM2 (R18 phase-3 verbatim) -> y
// Deadlock-free: deps form a DAG over fully co-resident blocks (512 = 2/CU,
// LDS 67 KB <= 80 KB, launch_bounds(256,2)).
// ---------------------------------------------------------------------------
__global__ __launch_bounds__(256, 2) void kF(
    const float* __restrict__ x, const short* __restrict__ Wf1,
    const float2* __restrict__ lampow2, const short* __restrict__ Wf2,
    float2* __restrict__ E, float* __restrict__ y,
    uint* __restrict__ flags) {
  __shared__ short bu[64 * 520];   // 65 KB
  __shared__ float2 Pl[N_ST];      // 2 KB carry exchange

  int bc = blockIdx.x;             // chunk id 0..511
  size_t row0 = (size_t)bc * CHUNK;
  int tid = threadIdx.x;
  int lane = tid & 63, w = tid >> 6;
  int m = lane & 15, q = lane >> 4;

  // ---- phase 0: GEMM1 (kA-verbatim structure) ----
  f32x4 acc[32];
#pragma unroll
  for (int ct = 0; ct < 32; ++ct) acc[ct] = (f32x4){0.f, 0.f, 0.f, 0.f};

  const float* xrowf = x + (row0 + 16 * w + m) * D_IN;

  for (int ks = 0; ks < 4; ++ks) {
    short8 af = cvt8(xrowf + 32 * ks + 8 * q);
    const short* wbase = Wf1 + ((size_t)(4 * ks + q) * 512 + m) * 8;
#pragma unroll
    for (int ct = 0; ct < 32; ++ct) {
      short8 bf = *(const short8*)(wbase + 16 * ct * 8);
      acc[ct] = __builtin_amdgcn_mfma_f32_16x16x32_bf16(af, bf, acc[ct], 0, 0, 0);
    }
  }

#pragma unroll
  for (int ct = 0; ct < 32; ++ct) {
#pragma unroll
    for (int r = 0; r < 4; ++r) {
      bu[(16 * w + 4 * q + r) * 520 + 16 * ct + m] = f2bf(acc[ct][r]);
    }
  }
  __syncthreads();

  // ---- phase 1: local scan in place (R18-verbatim) + E store + publish ----
  {
    int n = tid;
    float2 lam = lampow2[N_ST + n];  // lam^1
    float sre = 0.f, sim = 0.f;
    for (int j = 0; j < CHUNK; ++j) {
      uint p = ((const uint*)(bu + j * 520))[n];
      float br = bf2f(p & 0xffffu), bi = bf2f(p >> 16);
      float nr = fmaf(lam.x, sre, fmaf(-lam.y, sim, br));
      float ni = fmaf(lam.x, sim, fmaf(lam.y, sre, bi));
      sre = nr; sim = ni;
      ((uint*)(bu + j * 520))[n] = pack2(sre, sim);  // == old stored states bits
    }
    float2 e; e.x = sre; e.y = sim;
    E[bc * N_ST + n] = e;
  }
  __syncthreads();                 // all E stores drained (vmcnt before barrier)
  if (tid == 0) {
    __threadfence();               // release: L2 writeback -> coherence point
    atomicExch(flags + bc * 32, 1u);
  }

  // ---- phase 2: lookback. kB-verbatim forward recurrence -> P (bit-identical)
  {
    int b = bc >> 6, c = bc & 63;  // batch, chunk-in-batch
    if (tid < c) {
      uint* fl = flags + ((b << 6) | tid) * 32;
      while (atomicAdd(fl, 0u) == 0u) __builtin_amdgcn_s_sleep(8);
    }
    __syncthreads();
    __threadfence();               // acquire: invalidate stale cached copies

    int n = tid;
    float2 lamL = lampow2[CHUNK * N_ST + n];
    const float2* Eb = E + (size_t)(b << 6) * N_ST;
    float cre = 0.f, cim = 0.f;
    for (int i = 0; i < c; ++i) {
      float2 e = Eb[(size_t)i * N_ST + n];
      float nre = fmaf(lamL.x, cre, fmaf(-lamL.y, cim, e.x));
      float nim = fmaf(lamL.x, cim, fmaf(lamL.y, cre, e.y));
      cre = nre; cim = nim;
    }
    float2 pv; pv.x = cre; pv.y = cim;
    Pl[n] = pv;
  }
  __syncthreads();

  // ---- phase 3: carry fix-up in place (R18 phase-2 verbatim; P from LDS) ----
  {
    int n4 = tid & 63, rblk = tid >> 6;
    float4 pA = *(const float4*)(&Pl[4 * n4]);      // p0,p1
    float4 pB = *(const float4*)(&Pl[4 * n4 + 2]);  // p2,p3
#pragma unroll
    for (int rr = 0; rr < 16; ++rr) {
      int row = rblk * 16 + rr;    // local row 0..63
      uint4 sp = *(const uint4*)(bu + row * 520 + 8 * n4);
      float4 lpa = *(const float4*)(lampow2 + ((size_t)(row + 1) * N_ST + 4 * n4));
      float4 lpb = *(const float4*)(lampow2 + ((size_t)(row + 1) * N_ST + 4 * n4 + 2));
      uint4 outv;
      {
        float sr = bf2f(sp.x & 0xffffu) + lpa.x * pA.x - lpa.y * pA.y;
        float si = bf2f(sp.x >> 16)     + lpa.x * pA.y + lpa.y * pA.x;
        outv.x = pack2(sr, si);
      }
      {
        float sr = bf2f(sp.y & 0xffffu) + lpa.z * pA.z - lpa.w * pA.w;
        float si = bf2f(sp.y >> 16)     + lpa.z * pA.w + lpa.w * pA.z;
        outv.y = pack2(sr, si);
      }
      {
        float sr = bf2f(sp.z & 0xffffu) + lpb.x * pB.x - lpb.y * pB.y;
        float si = bf2f(sp.z >> 16)     + lpb.x * pB.y + lpb.y * pB.x;
        outv.z = pack2(sr, si);
      }
      {
        float sr = bf2f(sp.w & 0xffffu) + lpb.z * pB.z - lpb.w * pB.w;
        float si = bf2f(sp.w >> 16)     + lpb.z * pB.w + lpb.w * pB.z;
        outv.w = pack2(sr, si);
      }
      *(uint4*)(bu + row * 520 + 8 * n4) = outv;
    }
  }
  __syncthreads();

  // ---- phase 4: GEMM2 (R18 phase-3 verbatim; xa via cvt8 from x) ----
  int rw = w & 1, ch = w >> 1;
  int arow0 = 32 * rw + m;

  short8 xa0[4], xa1[4];
#pragma unroll
  for (int t = 0; t < 4; ++t) {
    xa0[t] = cvt8(x + (row0 + arow0) * D_IN + 32 * t + 8 * q);
    xa1[t] = cvt8(x + (row0 + arow0 + 16) * D_IN + 32 * t + 8 * q);
  }

  f32x4 acc2[2][4];                // [row-tile][col-tile]
#pragma unroll
  for (int rt = 0; rt < 2; ++rt)
#pragma unroll
    for (int ci = 0; ci < 4; ++ci) acc2[rt][ci] = (f32x4){0.f, 0.f, 0.f, 0.f};

  for (int ks = 0; ks < 16; ++ks) {
    int g = 4 * ks + q;
    short8 af0 = *(const short8*)(bu + arow0 * 520 + 8 * g);
    short8 af1 = *(const short8*)(bu + (arow0 + 16) * 520 + 8 * g);
    const short* wbase = Wf2 + ((size_t)g * 128 + m) * 8;
#pragma unroll
    for (int ci = 0; ci < 4; ++ci) {
      int ctg = 4 * ch + ci;
      short8 bf = *(const short8*)(wbase + 16 * ctg * 8);
      acc2[0][ci] = __builtin_amdgcn_mfma_f32_16x16x32_bf16(af0, bf, acc2[0][ci], 0, 0, 0);
      acc2[1][ci] = __builtin_amdgcn_mfma_f32_16x16x32_bf16(af1, bf, acc2[1][ci], 0, 0, 0);
    }
  }
#pragma unroll
  for (int t = 0; t < 4; ++t) {
    int g = 64 + 4 * t + q;
    const short* wbase = Wf2 + ((size_t)g * 128 + m) * 8;
#pragma unroll
    for (int ci = 0; ci < 4; ++ci) {
      int ctg = 4 * ch + ci;
      short8 bf = *(const short8*)(wbase + 16 * ctg * 8);
      acc2[0][ci] = __builtin_amdgcn_mfma_f32_16x16x32_bf16(xa0[t], bf, acc2[0][ci], 0, 0, 0);
      acc2[1][ci] = __builtin_amdgcn_mfma_f32_16x16x32_bf16(xa1[t], bf, acc2[1][ci], 0, 0, 0);
    }
  }

#pragma unroll
  for (int ci = 0; ci < 4; ++ci) {
    int ctg = 4 * ch + ci;
#pragma unroll
    for (int rt = 0; rt < 2; ++rt) {
#pragma unroll
      for (int r = 0; r < 4; ++r) {
        y[(row0 + 32 * rw + 16 * rt + 4 * q + r) * D_OUT + 16 * ctg + m] = acc2[rt][ci][r];
      }
    }
  }
}

// ---------------------------------------------------------------------------
extern "C" void kernel_launch(void* const* d_in, const int* in_sizes, int n_in,
                              void* d_out, int out_size, void* d_ws, size_t ws_size,
                              hipStream_t stream) {
  const float* x         = (const float*)d_in[0];
  const float* nu_log    = (const float*)d_in[1];
  const float* theta_log = (const float*)d_in[2];
  const float* gamma_log = (const float*)d_in[3];
  const float* B_re      = (const float*)d_in[4];
  const float* B_im      = (const float*)d_in[5];
  const float* C_re      = (const float*)d_in[6];
  const float* C_im      = (const float*)d_in[7];
  const float* Dm        = (const float*)d_in[8];
  float* y = (float*)d_out;

  char* wp = (char*)d_ws;
  float2* lampow2 = (float2*)wp; wp += (size_t)(CHUNK + 1) * N_ST * sizeof(float2);
  short*  Wf1     = (short*)wp;  wp += (size_t)16 * 512 * 8 * sizeof(short);
  short*  Wf2     = (short*)wp;  wp += (size_t)80 * 128 * 8 * sizeof(short);
  float2* E       = (float2*)wp; wp += (size_t)NBLK * N_ST * sizeof(float2);
  uint*   flags   = (uint*)wp;   wp += (size_t)NBLK * 32 * sizeof(uint);

  hipLaunchKernelGGL(k0w, dim3(385), dim3(256), 0, stream,
                     nu_log, theta_log, gamma_log, B_re, B_im, C_re, C_im,
                     Dm, Wf1, Wf2, lampow2, flags);
  hipLaunchKernelGGL(kF, dim3(NBLK), dim3(256), 0, stream,
                     x, Wf1, lampow2, Wf2, E, y, flags);
}

// Round 7
// 130.889 us; speedup vs baseline: 1.4542x; 1.3190x over previous
//
#include <hip/hip_runtime.h>
#include <math.h>

// Sizes (fixed by the problem)
#define B_SZ 8
#define T_LEN 4096
#define D_IN 128
#define D_OUT 128
#define N_ST 256
#define BT (B_SZ * T_LEN)        // 32768
#define CHUNK 64                 // scan chunk length
#define NCHUNK (T_LEN / CHUNK)   // 64 chunks per sequence
#define NBLK (B_SZ * NCHUNK)     // 512 chunk-blocks

typedef __attribute__((ext_vector_type(8))) short short8;
typedef __attribute__((ext_vector_type(4))) float f32x4;
typedef unsigned int uint;
typedef unsigned short ushort;

static __device__ __forceinline__ short f2bf(float f) {
  union { float f; uint u; } v; v.f = f;
  uint r = v.u + 0x7FFFu + ((v.u >> 16) & 1u);  // round-to-nearest-even
  return (short)(r >> 16);
}
static __device__ __forceinline__ float bf2f(uint h) {
  union { uint u; float f; } v; v.u = h << 16;
  return v.f;
}
static __device__ __forceinline__ uint pack2(float a, float b) {
  return (uint)(ushort)f2bf(a) | ((uint)(ushort)f2bf(b) << 16);
}
// 8 consecutive f32 -> short8 bf16; identical bits to the old k0 xbf pass
// (same pack2/f2bf rounding applied elementwise). Verified R20/R21.
static __device__ __forceinline__ short8 cvt8(const float* __restrict__ p) {
  float4 a = *(const float4*)p;
  float4 b = *(const float4*)(p + 4);
  union { short8 s; uint4 u; } r;
  r.u.x = pack2(a.x, a.y); r.u.y = pack2(a.z, a.w);
  r.u.z = pack2(b.x, b.y); r.u.w = pack2(b.z, b.w);
  return r.s;
}

// ---------------------------------------------------------------------------
// k0w: weights + lampow only (R12 expressions VERBATIM). Grid 385.
// The x->xbf pass is gone: kA/kC convert in-register (same bits).
// ---------------------------------------------------------------------------
__global__ __launch_bounds__(256) void k0w(
    const float* __restrict__ nu_log, const float* __restrict__ theta_log,
    const float* __restrict__ gamma_log,
    const float* __restrict__ B_re, const float* __restrict__ B_im,
    const float* __restrict__ C_re, const float* __restrict__ C_im,
    const float* __restrict__ Dm,
    short* __restrict__ Wf1, short* __restrict__ Wf2,
    float2* __restrict__ lampow2) {
  int blk = blockIdx.x;
  if (blk < 320) {
    int idx = blk * 256 + threadIdx.x;
    if (idx < 16 * 512 * 8) {
      int j = idx & 7, col = (idx >> 3) & 511, kg = idx >> 12;
      int k = kg * 8 + j;
      int n = col >> 1, ri = col & 1;
      float g = expf(gamma_log[n]);
      float v = g * (ri ? B_im[n * D_IN + k] : B_re[n * D_IN + k]);
      Wf1[idx] = f2bf(v);
    }
    if (idx < 80 * 128 * 8) {
      int j = idx & 7, d = (idx >> 3) & 127, kg = idx >> 10;
      int k = kg * 8 + j;
      float v;
      if (k < 512) {
        int n = k >> 1;
        v = (k & 1) ? -C_im[d * N_ST + n] : C_re[d * N_ST + n];
      } else {
        v = Dm[d * D_IN + (k - 512)];
      }
      Wf2[idx] = f2bf(v);
    }
  } else {
    int j = blk - 320;  // 0..64
    int n = threadIdx.x;
    float e_nu = expf(nu_log[n]);
    float phase = expf(theta_log[n]);
    float r = expf(-(float)j * e_nu);
    float a = (float)j * phase;
    float2 v; v.x = r * cosf(a); v.y = r * sinf(a);
    lampow2[j * N_ST + n] = v;
  }
}

// ---------------------------------------------------------------------------
// kA R22: R12 kA structure with two verified grafts:
//  (a) A-frags cvt8 from x f32 (bit-identical to xbf; verified R20/R21)
//  (b) scan writes pack2 in place into bu (verified R18/R20/R21), then a
//      bulk coalesced uint4 copy bu -> states (pure data movement of the
//      same bits; removes 64 per-thread stores from the serial chain).
// GEMM1/scan math & order VERBATIM -> states/E bits identical to R16.
// ---------------------------------------------------------------------------
__global__ __launch_bounds__(256, 2) void kA(
    const float* __restrict__ x, const short* __restrict__ Wf1,
    const float2* __restrict__ lampow2,
    uint* __restrict__ states, float2* __restrict__ E) {
  __shared__ short bu[64 * 520];   // row-major, +8 pad per row

  int bc = blockIdx.x;
  size_t row0 = (size_t)bc * CHUNK;
  int tid = threadIdx.x;
  int lane = tid & 63, w = tid >> 6;
  int m = lane & 15, q = lane >> 4;

  f32x4 acc[32];
#pragma unroll
  for (int ct = 0; ct < 32; ++ct) acc[ct] = (f32x4){0.f, 0.f, 0.f, 0.f};

  const float* xrowf = x + (row0 + 16 * w + m) * D_IN;

  for (int ks = 0; ks < 4; ++ks) {
    short8 af = cvt8(xrowf + 32 * ks + 8 * q);
    const short* wbase = Wf1 + ((size_t)(4 * ks + q) * 512 + m) * 8;
#pragma unroll
    for (int ct = 0; ct < 32; ++ct) {
      short8 bf = *(const short8*)(wbase + 16 * ct * 8);
      acc[ct] = __builtin_amdgcn_mfma_f32_16x16x32_bf16(af, bf, acc[ct], 0, 0, 0);
    }
  }

  // write Bu tile to LDS (bf16). C-layout: row=4q+r, col=m within 16x16 tile.
#pragma unroll
  for (int ct = 0; ct < 32; ++ct) {
#pragma unroll
    for (int r = 0; r < 4; ++r) {
      bu[(16 * w + 4 * q + r) * 520 + 16 * ct + m] = f2bf(acc[ct][r]);
    }
  }
  __syncthreads();

  // scan: thread n owns state n; pack2(s) written in place (R18-verified)
  {
    int n = tid;
    float2 lam = lampow2[N_ST + n];  // lam^1
    float sre = 0.f, sim = 0.f;
    for (int j = 0; j < CHUNK; ++j) {
      uint p = ((const uint*)(bu + j * 520))[n];
      float br = bf2f(p & 0xffffu), bi = bf2f(p >> 16);
      float nr = fmaf(lam.x, sre, fmaf(-lam.y, sim, br));
      float ni = fmaf(lam.x, sim, fmaf(lam.y, sre, bi));
      sre = nr; sim = ni;
      ((uint*)(bu + j * 520))[n] = pack2(sre, sim);  // same bits as old store
    }
    float2 e; e.x = sre; e.y = sim;
    E[bc * N_ST + n] = e;
  }
  __syncthreads();

  // bulk states copy: 64 rows x 64 uint4, fully coalesced (1 KB / wave-instr)
  for (int i = 0; i < 16; ++i) {
    int idx = i * 256 + tid;       // 0..4095
    int row = idx >> 6;            // 0..63
    int c4  = idx & 63;            // uint4 column
    ((uint4*)(states + (size_t)(row0 + row) * N_ST))[c4] =
        *(const uint4*)((const uint*)(bu + row * 520) + 4 * c4);
  }
}

// ---------------------------------------------------------------------------
// kC R22: R16 kC VERBATIM except:
//  (a) P global load -> per-block lookback over E (kB-verbatim FMA order,
//      verified R21; kernel boundary = sync, NO atomics/flags) -> Pl in LDS
//  (b) phase 1b reads x f32 and packs in-register (same bits as xbf copy)
// Row-split 64->32: As = 32x640 bf16 = 40 KB -> 4 blk/CU, 1024 blocks.
// ---------------------------------------------------------------------------
__global__ __launch_bounds__(256, 4) void kC(
    const float* __restrict__ x, const uint* __restrict__ states,
    const float2* __restrict__ E, const float2* __restrict__ lampow2,
    const short* __restrict__ Wf2, float* __restrict__ y) {
  __shared__ short As[32 * 640];   // 40 KB
  __shared__ float2 Pl[N_ST];      // 2 KB

  int blk = blockIdx.x;            // 0..1023
  int bc = blk >> 1;               // chunk id
  size_t row0 = (size_t)blk * 32;  // global time row base
  int tid = threadIdx.x;
  int n4 = tid & 63, rblk = tid >> 6;

  // ---- lookback: carry P(b,c) from E (kB-verbatim recurrence -> bit-identical)
  {
    int b = bc >> 6, c = bc & 63;  // batch, chunk-in-batch
    int n = tid;
    float2 lamL = lampow2[CHUNK * N_ST + n];
    const float2* Eb = E + (size_t)(b << 6) * N_ST;
    float cre = 0.f, cim = 0.f;
    for (int t = 0; t < NCHUNK; t += 8) {
      if (t >= c) break;
      float2 eb[8];
#pragma unroll
      for (int u = 0; u < 8; ++u)
        if (t + u < c) eb[u] = Eb[(size_t)(t + u) * N_ST + n];
#pragma unroll
      for (int u = 0; u < 8; ++u)
        if (t + u < c) {
          float nre = fmaf(lamL.x, cre, fmaf(-lamL.y, cim, eb[u].x));
          float nim = fmaf(lamL.x, cim, fmaf(lamL.y, cre, eb[u].y));
          cre = nre; cim = nim;
        }
    }
    float2 pv; pv.x = cre; pv.y = cim;
    Pl[n] = pv;
  }
  __syncthreads();

  // ---- P fragments for states 4*n4..4*n4+3 (same bits as old P loads) ----
  float4 pA = *(const float4*)(&Pl[4 * n4]);      // p0,p1
  float4 pB = *(const float4*)(&Pl[4 * n4 + 2]);  // p2,p3

  // phase 1b: x -> LDS bf16 (cols 512..639); pack2 from f32 == old xbf bits
  {
    int kxp = tid & 63, r0 = tid >> 6;
    int k = 512 + 2 * kxp;
    int g = k >> 3, koff = k & 7;
    for (int rr = 0; rr < 8; ++rr) {
      int row = r0 * 8 + rr;       // local row 0..31
      const float* xp = x + (row0 + row) * D_IN + 2 * kxp;
      uint xv = pack2(xp[0], xp[1]);
      int gp = (g & ~7) | ((g + row) & 7);
      *(uint*)(As + row * 640 + gp * 8 + koff) = xv;
    }
  }

  // phase 1a': vectorized states fix-up -> As cols 0..511 (R16 VERBATIM)
  {
    int j0 = (blk & 1) * 32;       // chunk-local row base
#pragma unroll
    for (int rr = 0; rr < 8; ++rr) {
      int row = rblk * 8 + rr;     // local row 0..31
      int j = j0 + row;            // chunk-local time
      uint4 sp = *(const uint4*)(states + ((row0 + row) * N_ST + 4 * n4));
      float4 lpa = *(const float4*)(lampow2 + ((size_t)(j + 1) * N_ST + 4 * n4));
      float4 lpb = *(const float4*)(lampow2 + ((size_t)(j + 1) * N_ST + 4 * n4 + 2));
      uint4 outv;
      {
        float sr = bf2f(sp.x & 0xffffu) + lpa.x * pA.x - lpa.y * pA.y;
        float si = bf2f(sp.x >> 16)     + lpa.x * pA.y + lpa.y * pA.x;
        outv.x = pack2(sr, si);
      }
      {
        float sr = bf2f(sp.y & 0xffffu) + lpa.z * pA.z - lpa.w * pA.w;
        float si = bf2f(sp.y >> 16)     + lpa.z * pA.w + lpa.w * pA.z;
        outv.y = pack2(sr, si);
      }
      {
        float sr = bf2f(sp.z & 0xffffu) + lpb.x * pB.x - lpb.y * pB.y;
        float si = bf2f(sp.z >> 16)     + lpb.x * pB.y + lpb.y * pB.x;
        outv.z = pack2(sr, si);
      }
      {
        float sr = bf2f(sp.w & 0xffffu) + lpb.z * pB.z - lpb.w * pB.w;
        float si = bf2f(sp.w >> 16)     + lpb.z * pB.w + lpb.w * pB.z;
        outv.w = pack2(sr, si);
      }
      int g = n4;
      int gp = (g & ~7) | ((g + row) & 7);
      *(uint4*)(As + row * 640 + gp * 8) = outv;
    }
  }
  __syncthreads();

  // phase 2: MFMA (R16 VERBATIM). wave w -> col-quarter, both row-tiles.
  int lane = tid & 63, w = tid >> 6;
  int m = lane & 15, q = lane >> 4;

  f32x4 acc[2][2];                 // [row-tile][col-tile]
#pragma unroll
  for (int rt = 0; rt < 2; ++rt)
#pragma unroll
    for (int ci = 0; ci < 2; ++ci) acc[rt][ci] = (f32x4){0.f, 0.f, 0.f, 0.f};

  for (int ks = 0; ks < 20; ++ks) {
    int g = 4 * ks + q;
    int gp = (g & ~7) | ((g + m) & 7);
    short8 af0 = *(const short8*)(As + m * 640 + gp * 8);
    short8 af1 = *(const short8*)(As + (16 + m) * 640 + gp * 8);
    const short* wbase = Wf2 + ((size_t)g * 128 + m) * 8;
#pragma unroll
    for (int ci = 0; ci < 2; ++ci) {
      int ctg = 2 * w + ci;
      short8 bf = *(const short8*)(wbase + 16 * ctg * 8);
      acc[0][ci] = __builtin_amdgcn_mfma_f32_16x16x32_bf16(af0, bf, acc[0][ci], 0, 0, 0);
      acc[1][ci] = __builtin_amdgcn_mfma_f32_16x16x32_bf16(af1, bf, acc[1][ci], 0, 0, 0);
    }
  }

#pragma unroll
  for (int ci = 0; ci < 2; ++ci) {
    int ctg = 2 * w + ci;
#pragma unroll
    for (int rt = 0; rt < 2; ++rt) {
#pragma unroll
      for (int r = 0; r < 4; ++r) {
        y[(row0 + 16 * rt + 4 * q + r) * D_OUT + 16 * ctg + m] = acc[rt][ci][r];
      }
    }
  }
}

// ---------------------------------------------------------------------------
extern "C" void kernel_launch(void* const* d_in, const int* in_sizes, int n_in,
                              void* d_out, int out_size, void* d_ws, size_t ws_size,
                              hipStream_t stream) {
  const float* x         = (const float*)d_in[0];
  const float* nu_log    = (const float*)d_in[1];
  const float* theta_log = (const float*)d_in[2];
  const float* gamma_log = (const float*)d_in[3];
  const float* B_re      = (const float*)d_in[4];
  const float* B_im      = (const float*)d_in[5];
  const float* C_re      = (const float*)d_in[6];
  const float* C_im      = (const float*)d_in[7];
  const float* Dm        = (const float*)d_in[8];
  float* y = (float*)d_out;

  char* wp = (char*)d_ws;
  float2* lampow2 = (float2*)wp; wp += (size_t)(CHUNK + 1) * N_ST * sizeof(float2);
  short*  Wf1     = (short*)wp;  wp += (size_t)16 * 512 * 8 * sizeof(short);
  short*  Wf2     = (short*)wp;  wp += (size_t)80 * 128 * 8 * sizeof(short);
  float2* E       = (float2*)wp; wp += (size_t)NBLK * N_ST * sizeof(float2);
  uint*   states  = (uint*)wp;   wp += (size_t)BT * N_ST * sizeof(uint);

  hipLaunchKernelGGL(k0w, dim3(385), dim3(256), 0, stream,
                     nu_log, theta_log, gamma_log, B_re, B_im, C_re, C_im,
                     Dm, Wf1, Wf2, lampow2);
  hipLaunchKernelGGL(kA, dim3(NBLK), dim3(256), 0, stream,
                     x, Wf1, lampow2, states, E);
  hipLaunchKernelGGL(kC, dim3(2 * NBLK), dim3(256), 0, stream,
                     x, states, E, lampow2, Wf2, y);
}